// Round 5
// baseline (312.736 us; speedup 1.0000x reference)
//
#include <hip/hip_runtime.h>
#include <stdint.h>

// Problem constants: B=8, P=4096, N=1024, H=W=1024, labels 0..1024
#define PPTS 4096
#define NGT  1024
#define HH   1024
#define WW   1024
#define EVC  3584        // LDS event capacity (E[total dumps] ~2600); global spill beyond
#define BGCAP 192        // max bg steps (E[m] ~65)

typedef unsigned long long u64;

__device__ __forceinline__ float pdist(float vx, float vy, float ux, float uy) {
    float dx = __fsub_rn(vx, ux);
    float dy = __fsub_rn(vy, uy);
    return __fsqrt_rn(__fadd_rn(__fmul_rn(dx, dx), __fmul_rn(dy, dy)));
}

// One block per batch.
//  A-D : stage U in regs, label points, counting-sort coords+ids into per-label
//        buckets (contiguous!), key-occurrence lists, bg0 bitmask + reg flags.
//  1a  : one thread per label runs its inside-match chain (contiguous bucket reads).
//  1b  : replay, emit dump-event SLOTS j-sorted into evPool (+global p spill).
//  stg : one-shot staging: evPool slots -> contiguous evCoord/evPid (aliased
//        over dead bucketC/ldsEnt via read-regs-sync-write).
//  a   : bg0 mins: transposed, coords in regs, filtered LDS atomicMin u64.
//  b   : event mins: per-step contiguous evCoord scan, one butterfly/step;
//        combine with stepMin -> specWin.
//  2c  : dup-check -> parallel commit (exact) or sequential fallback walk.
__global__ __launch_bounds__(1024) void matcher_kernel(
    const float* __restrict__ pred,    // [B,P,2]
    const float* __restrict__ coords,  // [B,N,2]
    const int*   __restrict__ keys,    // [B,N]
    const int*   __restrict__ masks,   // [B,H,W]
    float* __restrict__ out,           // [B*N src][B*N tgt][B total]
    unsigned short* __restrict__ evGlobAll, int evCapG, int B)
{
    __shared__ __align__(16) char regU[32768];   // bucketC f2[4096] -> evCoord f2[EVC]
    __shared__ __align__(8)  char regE[8192];    // ldsEnt u16[4096] -> evPid u16[EVC]
    __shared__ __align__(8)  char regB[8200];    // bEnd i32[1025]+occA i32[1025] -> specWin u64[BGCAP]
    __shared__ __align__(8)  char regP[2 * EVC]; // evPool u16[EVC] -> stepMin u64[BGCAP]
    __shared__ __align__(4)  char regS[384];     // present u32[33] -> bgListSh u16[BGCAP]
    __shared__ __align__(8)  char regW[128];     // wave scratch: u64[16]/int[16]/float[16]
    __shared__ unsigned short evAx[1025];        // exclusive event offsets (u16 ok: ~2600)
    __shared__ unsigned short occList[NGT];
    __shared__ short          matchU[NGT];
    __shared__ unsigned       bgbits[PPTS / 32];
    __shared__ float2         vSteps[BGCAP];
    __shared__ int            scal[8];           // 0:bgCnt 1:- 2:dupFlag 3:totEv

    float2*         bucketC = (float2*)regU;
    float2*         evCoord = (float2*)regU;
    unsigned short* ldsEnt  = (unsigned short*)regE;
    unsigned short* evPid   = (unsigned short*)regE;
    int*            bEnd    = (int*)regB;
    int*            occA    = ((int*)regB) + 1025;
    u64*            specWin = (u64*)regB;
    unsigned short* evPool  = (unsigned short*)regP;
    u64*            stepMin = (u64*)regP;
    unsigned*       present = (unsigned*)regS;
    unsigned short* bgListSh = (unsigned short*)regS;
    u64*   wScr64 = (u64*)regW;
    int*   wScrI  = (int*)regW;
    float* wScrF  = (float*)regW;

    const int b = blockIdx.x;
    const int t = threadIdx.x;
    const int lane = t & 63, wv = t >> 6;
    const float* Ub = pred   + (size_t)b * PPTS * 2;
    const float* Vb = coords + (size_t)b * NGT * 2;
    const int*   Kb = keys   + (size_t)b * NGT;
    const int*   Mb = masks  + (size_t)b * HH * WW;
    unsigned short* evGlobB = evGlobAll + (size_t)b * (size_t)evCapG;

    // ---- A: zero ----
    bEnd[t] = 0; occA[t] = 0; evAx[t] = 0;
    if (t == 0) { bEnd[1024] = 0; occA[1024] = 0; evAx[1024] = 0;
                  scal[0] = 0; scal[2] = 0; scal[3] = 0; }
    if (t < PPTS / 32) bgbits[t] = 0;
    if (t < 33) present[t] = 0;
    __syncthreads();

    // ---- B: histograms + mask gather; point coords stay in registers ----
    const int k1 = Kb[t] + 1;                    // label of step j=t, in [1,1024]
    atomicOr(&present[k1 >> 5], 1u << (k1 & 31));
    atomicAdd(&occA[k1], 1);
    int lab[4]; float2 up[4];
    #pragma unroll
    for (int i = 0; i < 4; i++) {
        int p = t + (i << 10);
        float2 u = ((const float2*)Ub)[p];
        up[i] = u;
        int xi = (int)rintf(__fmul_rn(u.x, 1024.0f));  // rintf == jnp.round (half-even)
        int yi = (int)rintf(__fmul_rn(u.y, 1024.0f));
        xi = min(max(xi, 0), HH - 1);
        yi = min(max(yi, 0), WW - 1);
        lab[i] = Mb[xi * WW + yi];
        atomicAdd(&bEnd[lab[i]], 1);
    }
    __syncthreads();

    // ---- C: joint EXCLUSIVE scan of bEnd & occA (packed u64, 2 barriers) ----
    {
        int a = bEnd[t], c = occA[t];
        u64 pk = ((u64)(unsigned)a << 32) | (unsigned)c;
        u64 inc = pk;
        #pragma unroll
        for (int off = 1; off < 64; off <<= 1) {
            u64 n = __shfl_up(inc, off, 64);
            if (lane >= off) inc += n;
        }
        if (lane == 63) wScr64[wv] = inc;
        __syncthreads();
        if (t < 16) {
            u64 v = wScr64[t], inc2 = v;
            #pragma unroll
            for (int off = 1; off < 16; off <<= 1) {
                u64 n = __shfl_up(inc2, off, 64);
                if (t >= off) inc2 += n;
            }
            wScr64[t] = inc2 - v;
        }
        __syncthreads();
        u64 excl = wScr64[wv] + inc - pk;
        int ea = (int)(excl >> 32), ec = (int)(excl & 0xFFFFFFFFu);
        bEnd[t] = ea; occA[t] = ec;
        if (t == 1023) { bEnd[1024] = ea + a; occA[1024] = ec + c; }
    }
    __syncthreads();

    // ---- D: scatter coords+ids into buckets, occ lists, bg0 mask+flags ----
    int bg0m = 0;
    #pragma unroll
    for (int i = 0; i < 4; i++) {
        int p = t + (i << 10);
        int slot = atomicAdd(&bEnd[lab[i]], 1);
        ldsEnt[slot] = (unsigned short)p;
        bucketC[slot] = up[i];
        if (!((present[lab[i] >> 5] >> (lab[i] & 31)) & 1u)) {
            bg0m |= 1 << i;
            atomicOr(&bgbits[p >> 5], 1u << (p & 31));
        }
    }
    {
        int slot = atomicAdd(&occA[k1], 1);
        occList[slot] = (unsigned short)t;
    }
    __syncthreads();

    // ---- 1a: per-label inside-match chains (thread t -> label t+1) ----
    float costPartial = 0.0f;
    {
        const int l = t + 1;
        const int os = occA[l - 1], oe = occA[l];
        for (int i = os + 1; i < oe; i++) {          // sort occurrences ascending
            unsigned short v = occList[i];
            int k = i - 1;
            while (k >= os && occList[k] > v) { occList[k + 1] = occList[k]; k--; }
            occList[k + 1] = v;
        }
        const int bs = bEnd[l - 1], be = bEnd[l];
        u64 cons = 0;
        for (int o = os; o < oe; o++) {
            int j = occList[o];
            float2 v = ((const float2*)Vb)[j];
            u64 best = ~0ull;
            int avail = 0;
            for (int e = bs; e < be; e++) {
                int eIdx = e - bs;
                int p = ldsEnt[e];
                bool consd;
                if (eIdx < 64) consd = (cons >> eIdx) & 1ull;
                else {
                    consd = false;
                    for (int o2 = os; o2 < o; o2++)
                        if ((int)matchU[occList[o2]] == p) { consd = true; break; }
                }
                if (consd) continue;
                avail++;
                float2 u = bucketC[e];
                float d = pdist(v.x, v.y, u.x, u.y);
                u64 pk = ((u64)__float_as_uint(d) << 24) | ((u64)(unsigned)p << 12)
                         | (u64)(unsigned)eIdx;
                if (pk < best) best = pk;
            }
            if (avail > 0) {
                int eW = (int)(best & 0xFFFull);
                int pW = (int)((best >> 12) & 0xFFFull);
                costPartial = __fadd_rn(costPartial, __uint_as_float((unsigned)(best >> 24)));
                matchU[j] = (short)pW;
                if (eW < 64) cons |= 1ull << eW;
                evAx[j] = (unsigned short)(avail - 1);
            } else {
                matchU[j] = -2;
            }
        }
    }
    __syncthreads();

    // ---- evAx EXCLUSIVE scan (2 barriers) ----
    {
        int v = evAx[t], inc = v;
        #pragma unroll
        for (int off = 1; off < 64; off <<= 1) {
            int n = __shfl_up(inc, off, 64);
            if (lane >= off) inc += n;
        }
        if (lane == 63) wScrI[wv] = inc;
        __syncthreads();
        if (t < 16) {
            int s0 = wScrI[t], inc2 = s0;
            #pragma unroll
            for (int off = 1; off < 16; off <<= 1) {
                int n = __shfl_up(inc2, off, 64);
                if (t >= off) inc2 += n;
            }
            wScrI[t] = inc2 - s0;
        }
        __syncthreads();
        int excl = wScrI[wv] + inc - v;
        evAx[t] = (unsigned short)excl;
        if (t == 1023) scal[3] = excl + v;            // total events
    }
    __syncthreads();

    // ---- bg-step list compaction (ascending j) ----
    {
        bool need = (matchU[t] == (short)-2);
        u64 m = __ballot(need);
        if (lane == 0) wScrI[wv] = __popcll(m);
    }
    __syncthreads();
    if (t < 64) {
        int orig = (t < 16) ? wScrI[t] : 0;
        int v = orig;
        #pragma unroll
        for (int off = 1; off <= 8; off <<= 1) {
            int n = __shfl_up(v, off, 64);
            if (t >= off) v += n;
        }
        if (t < 16) wScrI[t] = v - orig;
        if (t == 15) scal[0] = v;
    }
    __syncthreads();
    {
        bool need = (matchU[t] == (short)-2);
        u64 m = __ballot(need);
        if (need) {
            int rank = __popcll(m & ((1ull << lane) - 1ull));
            int idx = wScrI[wv] + rank;
            if (idx < BGCAP) bgListSh[idx] = (unsigned short)t;
        }
    }
    __syncthreads();

    // ---- 1b: replay, emit dump-event slots (j-sorted by construction) ----
    {
        const int l = t + 1;
        const int os = occA[l - 1], oe = occA[l];
        const int bs = bEnd[l - 1], be = bEnd[l];
        u64 cons = 0;
        for (int o = os; o < oe; o++) {
            int j = occList[o];
            int u = matchU[j];
            if (u < 0) continue;
            int w2 = evAx[j];
            for (int e = bs; e < be; e++) {
                int eIdx = e - bs;
                int p = ldsEnt[e];
                bool consd;
                if (eIdx < 64) consd = (cons >> eIdx) & 1ull;
                else {
                    consd = false;
                    for (int o2 = os; o2 < o; o2++)
                        if ((int)matchU[occList[o2]] == p) { consd = true; break; }
                }
                if (consd) continue;
                if (p == u) { if (eIdx < 64) cons |= 1ull << eIdx; }
                else {
                    if (w2 < EVC) evPool[w2] = (unsigned short)e;          // slot
                    else if (w2 - EVC < evCapG) evGlobB[w2 - EVC] = (unsigned short)p;
                    ++w2;
                }
            }
        }
    }
    __syncthreads();

    // ---- staging: slots -> contiguous evCoord/evPid (regs, sync, write) ----
    const int bgCnt = min(scal[0], BGCAP);
    {
        const int nStage = min(scal[3], EVC);
        float2 sc[4]; unsigned short sp[4];
        int nMy = 0;
        for (int i = t; i < nStage; i += 1024) {
            int slot = evPool[i];
            sp[nMy] = ldsEnt[slot];
            sc[nMy] = bucketC[slot];
            nMy++;
        }
        __syncthreads();
        int k = 0;
        for (int i = t; i < nStage; i += 1024) {
            evCoord[i] = sc[k];
            evPid[i] = sp[k];
            k++;
        }
        if (t < BGCAP) stepMin[t] = ~0ull;
        if (t < bgCnt) vSteps[t] = ((const float2*)Vb)[bgListSh[t]];
    }
    __syncthreads();

    // ---- alpha: bg0 mins, transposed, filtered LDS atomicMin ----
    for (int s = 0; s < bgCnt; ++s) {
        float2 v = vSteps[s];
        unsigned curHi = ((unsigned*)&stepMin[s])[1];   // stale-ok filter (monotone dec)
        #pragma unroll
        for (int i = 0; i < 4; ++i) {
            if ((bg0m >> i) & 1) {
                float d = pdist(v.x, v.y, up[i].x, up[i].y);
                unsigned db = __float_as_uint(d);
                if (db <= curHi) {
                    u64 pk = ((u64)db << 32) | (unsigned)(t + (i << 10));
                    atomicMin(&stepMin[s], pk);
                    curHi = db;
                }
            }
        }
    }
    __syncthreads();

    // ---- beta: event mins (contiguous scans), combine -> specWin ----
    for (int s = wv; s < bgCnt; s += 16) {
        int js = bgListSh[s];
        float2 v = vSteps[s];
        int ne = evAx[js];
        u64 best = ~0ull;
        for (int i = lane; i < ne; i += 64) {
            float2 c; unsigned p;
            if (i < EVC) { c = evCoord[i]; p = evPid[i]; }
            else { p = evGlobB[i - EVC]; c = ((const float2*)Ub)[p]; }
            float d = pdist(v.x, v.y, c.x, c.y);
            u64 pk = ((u64)__float_as_uint(d) << 32) | p;
            if (pk < best) best = pk;
        }
        #pragma unroll
        for (int off = 32; off >= 1; off >>= 1) {
            u64 o = __shfl_xor(best, off, 64);
            if (o < best) best = o;
        }
        if (lane == 0) {
            u64 a = stepMin[s];
            specWin[s] = (best < a) ? best : a;
        }
    }
    __syncthreads();

    // ---- 2c: duplicate-winner check; parallel commit or sequential walk ----
    if (t < bgCnt) {
        u64 w0 = specWin[t];
        if (w0 != ~0ull) {
            unsigned myp = (unsigned)(w0 & 0xFFFFFFFFull);
            for (int s2 = 0; s2 < t; s2++) {
                u64 ws = specWin[s2];
                if (ws != ~0ull && (unsigned)(ws & 0xFFFFFFFFull) == myp) { scal[2] = 1; break; }
            }
        }
    }
    __syncthreads();
    float bgCost = 0.0f;
    if (scal[2] == 0) {
        // all winners distinct -> every speculative winner exact
        if (t < bgCnt) {
            int js = bgListSh[t];
            u64 w0 = specWin[t];
            if (w0 == ~0ull) matchU[js] = -1;
            else {
                matchU[js] = (short)(w0 & 0xFFFFFFFFull);
                costPartial = __fadd_rn(costPartial, __uint_as_float((unsigned)(w0 >> 32)));
            }
        }
    } else if (t < 64) {
        // sequential walk: apply events, O(1) validity check, rare recompute
        int applied = 0;
        for (int s = 0; s < bgCnt; s++) {
            int js = bgListSh[s];
            int target = evAx[js];
            for (int base = applied; base < target; base += 64) {
                int idx = base + t;
                if (idx < target) {
                    int p = (idx < EVC) ? (int)evPid[idx] : (int)evGlobB[idx - EVC];
                    atomicOr(&bgbits[p >> 5], 1u << (p & 31));
                }
            }
            applied = target;
            __threadfence_block();
            u64 w0 = specWin[s];
            if (w0 == ~0ull) {
                if (t == 0) matchU[js] = -1;
            } else {
                int u = (int)(w0 & 0xFFFFFFFFull);
                bool setb = (bgbits[u >> 5] >> (u & 31)) & 1u;
                if (setb) {
                    if (t == 0) {
                        matchU[js] = (short)u;
                        atomicAnd(&bgbits[u >> 5], ~(1u << (u & 31)));
                        bgCost = __fadd_rn(bgCost, __uint_as_float((unsigned)(w0 >> 32)));
                    }
                } else {
                    float2 v = vSteps[s];
                    u64 best = ~0ull;
                    #pragma unroll
                    for (int i = 0; i < 2; i++) {
                        int wi = t * 2 + i;
                        unsigned bits = bgbits[wi];
                        int pb = wi << 5;
                        while (bits) {
                            int bpos = __builtin_ctz(bits);
                            bits &= bits - 1;
                            int p = pb + bpos;
                            float2 uu = ((const float2*)Ub)[p];   // rare: global coords
                            float d = pdist(v.x, v.y, uu.x, uu.y);
                            u64 pk = ((u64)__float_as_uint(d) << 32) | (unsigned)p;
                            if (pk < best) best = pk;
                        }
                    }
                    #pragma unroll
                    for (int off = 32; off >= 1; off >>= 1) {
                        u64 o = __shfl_xor(best, off, 64);
                        if (o < best) best = o;
                    }
                    if (t == 0) {
                        if (best != ~0ull) {
                            int u2 = (int)(best & 0xFFFFFFFFull);
                            matchU[js] = (short)u2;
                            atomicAnd(&bgbits[u2 >> 5], ~(1u << (u2 & 31)));
                            bgCost = __fadd_rn(bgCost, __uint_as_float((unsigned)(best >> 32)));
                        } else matchU[js] = -1;
                    }
                }
                __threadfence_block();
            }
        }
    }
    __syncthreads();

    // ---- epilogue: cost reduction + outputs ----
    {
        float cp = costPartial;
        #pragma unroll
        for (int off = 32; off >= 1; off >>= 1) cp += __shfl_xor(cp, off, 64);
        if (lane == 0) wScrF[wv] = cp;
    }
    __syncthreads();
    if (t == 0) {
        float tot = bgCost;
        for (int i = 0; i < 16; ++i) tot = __fadd_rn(tot, wScrF[i]);
        out[(size_t)2 * B * NGT + b] = tot;
    }
    {
        int u = matchU[t];
        out[(size_t)b * NGT + t] = (float)u;
        out[(size_t)B * NGT + (size_t)b * NGT + t] = (u >= 0) ? (float)t : -1.0f;
    }
}

extern "C" void kernel_launch(void* const* d_in, const int* in_sizes, int n_in,
                              void* d_out, int out_size, void* d_ws, size_t ws_size,
                              hipStream_t stream) {
    const float* pred   = (const float*)d_in[0];
    const float* coords = (const float*)d_in[1];
    const int*   keys   = (const int*)d_in[2];
    const int*   masks  = (const int*)d_in[3];
    float* out = (float*)d_out;
    int B = in_sizes[2] / NGT;   // 8
    int evCapG = (int)((ws_size / (size_t)B) / sizeof(unsigned short));
    matcher_kernel<<<B, 1024, 0, stream>>>(pred, coords, keys, masks, out,
                                           (unsigned short*)d_ws, evCapG, B);
}

// Round 6
// 185.556 us; speedup vs baseline: 1.6854x; 1.6854x over previous
//
#include <hip/hip_runtime.h>
#include <stdint.h>

// Problem constants: B=8, P=4096, N=1024, H=W=1024, labels 0..1024
#define PPTS 4096
#define NGT  1024
#define HH   1024
#define WW   1024
#define EVPOOL_CAP 3072   // LDS event-slot pool (totEv <= 3400 proven r4; spill -> global)
#define BGCAP 160         // max bg steps (E[m] ~65)
#define M21 0x1FFFFFu

typedef unsigned long long u64;

__device__ __forceinline__ float pdist(float vx, float vy, float ux, float uy) {
    float dx = __fsub_rn(vx, ux);
    float dy = __fsub_rn(vy, uy);
    return __fsqrt_rn(__fadd_rn(__fmul_rn(dx, dx), __fmul_rn(dy, dy)));
}

// One block per batch.
//  A-B : zero, histograms (label counts, occ counts), mask gather, U in regs.
//  C   : triple-packed u64 scan (bg<<42 | present<<21 | occ) -> BG-FIRST
//        counting-sort offsets: bg buckets occupy [0,nBg0), present [nBg0,4096).
//  D   : scatter coords+ids (bg0 list = bucketC/ldsEnt[0..nBg0) for free).
//  1a  : one thread per label: inside-match chain (contiguous bucket reads).
//  1b  : replay, emit dump-event slots j-sorted into evPool (+global spill).
//  stg : slots -> staged events at bucketC/ldsEnt[nBg0..nBg0+EVcap) (unrolled
//        fixed-index regs; no scratch). Candidate pool is now ONE linear array.
//  beta: speculative per-step argmin = branch-free contiguous scan of
//        [0, nBg0+ne), one wave per step, one butterfly per step.
//  2c  : dup-check -> parallel commit (exact) or sequential fallback walk.
__global__ __launch_bounds__(1024) void matcher_kernel(
    const float* __restrict__ pred,    // [B,P,2]
    const float* __restrict__ coords,  // [B,N,2]
    const int*   __restrict__ keys,    // [B,N]
    const int*   __restrict__ masks,   // [B,H,W]
    float* __restrict__ out,           // [B*N src][B*N tgt][B total]
    unsigned short* __restrict__ evGlobAll, int evCapG, int B)
{
    __shared__ __align__(16) char regU[32768];          // bucketC f2[4096] (bg0C + staged evCoord)
    __shared__ __align__(8)  char regE[8192];           // ldsEnt u16[4096] (bg0P + staged evPid)
    __shared__ __align__(8)  char regB[8200];           // bEnd[1025]+occA[1025] -> specWin u64[BGCAP]
    __shared__ __align__(8)  char regP[2 * EVPOOL_CAP]; // evPool u16 -> vSteps f2[BGCAP]
    __shared__ __align__(4)  char regS[384];            // present u32[33] -> bgListSh u16[BGCAP]
    __shared__ u64            wScr64[16];               // wave scratch (u64/int/float views)
    __shared__ u64            sTot;                     // grand total of triple scan
    __shared__ unsigned short evAx[1024];               // exclusive event offsets per step
    __shared__ unsigned short occList[NGT];
    __shared__ short          matchU[NGT];
    __shared__ unsigned       bgbits[PPTS / 32];
    __shared__ unsigned short bSt[1024];                // bucket start of label t+1
    __shared__ int            scal[8];                  // 0:bgCnt 2:dupFlag 3:totEv

    float2*         bucketC  = (float2*)regU;
    unsigned short* ldsEnt   = (unsigned short*)regE;
    int*            bEnd     = (int*)regB;
    int*            occA     = ((int*)regB) + 1025;
    u64*            specWin  = (u64*)regB;
    unsigned short* evPool   = (unsigned short*)regP;
    float2*         vSteps   = (float2*)regP;
    unsigned*       present  = (unsigned*)regS;
    unsigned short* bgListSh = (unsigned short*)regS;
    int*   wScrI = (int*)wScr64;
    float* wScrF = (float*)wScr64;

    const int b = blockIdx.x;
    const int t = threadIdx.x;
    const int lane = t & 63, wv = t >> 6;
    const float* Ub = pred   + (size_t)b * PPTS * 2;
    const float* Vb = coords + (size_t)b * NGT * 2;
    const int*   Kb = keys   + (size_t)b * NGT;
    const int*   Mb = masks  + (size_t)b * HH * WW;
    unsigned short* evGlobB = evGlobAll + (size_t)b * (size_t)evCapG;

    // ---- A: zero ----
    bEnd[t] = 0; occA[t] = 0; evAx[t] = 0;
    if (t == 0) { bEnd[1024] = 0; occA[1024] = 0; scal[0] = 0; scal[2] = 0; scal[3] = 0; }
    if (t < PPTS / 32) bgbits[t] = 0;
    if (t < 33) present[t] = 0;
    __syncthreads();

    // ---- B: histograms + mask gather; point coords stay in registers ----
    const int k1 = Kb[t] + 1;                    // label of step j=t, in [1,1024]
    atomicOr(&present[k1 >> 5], 1u << (k1 & 31));
    atomicAdd(&occA[k1], 1);
    int lab[4]; float2 up[4];
    #pragma unroll
    for (int i = 0; i < 4; i++) {
        int p = t + (i << 10);
        float2 u = ((const float2*)Ub)[p];
        up[i] = u;
        int xi = (int)rintf(__fmul_rn(u.x, 1024.0f));  // rintf == jnp.round (half-even)
        int yi = (int)rintf(__fmul_rn(u.y, 1024.0f));
        xi = min(max(xi, 0), HH - 1);
        yi = min(max(yi, 0), WW - 1);
        lab[i] = Mb[xi * WW + yi];
        atomicAdd(&bEnd[lab[i]], 1);
    }
    __syncthreads();

    // ---- C: triple-packed exclusive scan -> bg-first bucket starts ----
    {
        int c0 = bEnd[t], o0 = occA[t];
        bool pr0 = (present[t >> 5] >> (t & 31)) & 1u;
        u64 myv = (pr0 ? ((u64)(unsigned)c0 << 21) : ((u64)(unsigned)c0 << 42))
                  | (u64)(unsigned)o0;
        u64 add1 = 0;
        bool pr1 = false; int c1 = 0, o1 = 0;
        if (t == 1023) {                          // fold label 1024 into last thread
            c1 = bEnd[1024]; o1 = occA[1024];
            pr1 = present[32] & 1u;
            add1 = (pr1 ? ((u64)(unsigned)c1 << 21) : ((u64)(unsigned)c1 << 42))
                   | (u64)(unsigned)o1;
        }
        u64 tot = myv + add1;
        u64 inc = tot;
        #pragma unroll
        for (int off = 1; off < 64; off <<= 1) {
            u64 n = __shfl_up(inc, off, 64);
            if (lane >= off) inc += n;
        }
        if (lane == 63) wScr64[wv] = inc;
        __syncthreads();
        if (t < 16) {
            u64 v = wScr64[t], inc2 = v;
            #pragma unroll
            for (int off = 1; off < 16; off <<= 1) {
                u64 n = __shfl_up(inc2, off, 64);
                if (t >= off) inc2 += n;
            }
            wScr64[t] = inc2 - v;
            if (t == 15) sTot = inc2;
        }
        __syncthreads();
        u64 excl = wScr64[wv] + inc - tot;
        int nBg0v = (int)(sTot >> 42);
        int bgS = (int)(excl >> 42);
        int prS = (int)((excl >> 21) & M21);
        int ocS = (int)(excl & M21);
        int start0 = pr0 ? (nBg0v + prS) : bgS;
        bEnd[t] = start0;                         // scatter cursor (start)
        occA[t] = ocS;
        if (t >= 1) bSt[t - 1] = (unsigned short)start0;  // start of label t
        if (t == 1023) {
            u64 ex1 = excl + myv;
            int bgS1 = (int)(ex1 >> 42);
            int prS1 = (int)((ex1 >> 21) & M21);
            int start1 = pr1 ? (nBg0v + prS1) : bgS1;
            bEnd[1024] = start1; occA[1024] = (int)(ex1 & M21);
            bSt[1023] = (unsigned short)start1;   // start of label 1024
        }
    }
    __syncthreads();
    const int nBg0 = (int)(sTot >> 42);
    const int EVcap = min(EVPOOL_CAP, PPTS - nBg0);

    // ---- D: scatter coords+ids (bg labels land in [0,nBg0)), occ lists ----
    #pragma unroll
    for (int i = 0; i < 4; i++) {
        int p = t + (i << 10);
        int slot = atomicAdd(&bEnd[lab[i]], 1);
        ldsEnt[slot] = (unsigned short)p;
        bucketC[slot] = up[i];
        if (!((present[lab[i] >> 5] >> (lab[i] & 31)) & 1u))
            atomicOr(&bgbits[p >> 5], 1u << (p & 31));   // fallback path only
    }
    {
        int slot = atomicAdd(&occA[k1], 1);
        occList[slot] = (unsigned short)t;
    }
    __syncthreads();

    // ---- 1a: per-label inside-match chains (thread t -> label t+1) ----
    float costPartial = 0.0f;
    {
        const int l = t + 1;
        const int os = occA[t], oe = occA[l];    // post-scatter: end(t)=start(l), end(l)
        for (int i = os + 1; i < oe; i++) {      // sort occurrences ascending
            unsigned short v = occList[i];
            int k = i - 1;
            while (k >= os && occList[k] > v) { occList[k + 1] = occList[k]; k--; }
            occList[k + 1] = v;
        }
        const int bs = bSt[t], be = bEnd[l];
        u64 cons = 0;
        for (int o = os; o < oe; o++) {
            int j = occList[o];
            float2 v = ((const float2*)Vb)[j];
            u64 best = ~0ull;
            int avail = 0;
            for (int e = bs; e < be; e++) {
                int eIdx = e - bs;
                int p = ldsEnt[e];
                bool consd;
                if (eIdx < 64) consd = (cons >> eIdx) & 1ull;
                else {
                    consd = false;
                    for (int o2 = os; o2 < o; o2++)
                        if ((int)matchU[occList[o2]] == p) { consd = true; break; }
                }
                if (consd) continue;
                avail++;
                float2 u = bucketC[e];
                float d = pdist(v.x, v.y, u.x, u.y);
                u64 pk = ((u64)__float_as_uint(d) << 24) | ((u64)(unsigned)p << 12)
                         | (u64)(unsigned)eIdx;
                if (pk < best) best = pk;
            }
            if (avail > 0) {
                int eW = (int)(best & 0xFFFull);
                int pW = (int)((best >> 12) & 0xFFFull);
                costPartial = __fadd_rn(costPartial, __uint_as_float((unsigned)(best >> 24)));
                matchU[j] = (short)pW;
                if (eW < 64) cons |= 1ull << eW;
                evAx[j] = (unsigned short)(avail - 1);
            } else {
                matchU[j] = -2;
            }
        }
    }
    __syncthreads();

    // ---- evAx EXCLUSIVE scan (2 barriers) ----
    {
        int v = evAx[t], inc = v;
        #pragma unroll
        for (int off = 1; off < 64; off <<= 1) {
            int n = __shfl_up(inc, off, 64);
            if (lane >= off) inc += n;
        }
        if (lane == 63) wScrI[wv] = inc;
        __syncthreads();
        if (t < 16) {
            int s0 = wScrI[t], inc2 = s0;
            #pragma unroll
            for (int off = 1; off < 16; off <<= 1) {
                int n = __shfl_up(inc2, off, 64);
                if (t >= off) inc2 += n;
            }
            wScrI[t] = inc2 - s0;
        }
        __syncthreads();
        int excl = wScrI[wv] + inc - v;
        evAx[t] = (unsigned short)excl;
        if (t == 1023) scal[3] = excl + v;       // total events
    }
    __syncthreads();

    // ---- bg-step list compaction (ascending j) ----
    {
        bool need = (matchU[t] == (short)-2);
        u64 m = __ballot(need);
        if (lane == 0) wScrI[wv] = __popcll(m);
    }
    __syncthreads();
    if (t < 64) {
        int orig = (t < 16) ? wScrI[t] : 0;
        int v = orig;
        #pragma unroll
        for (int off = 1; off <= 8; off <<= 1) {
            int n = __shfl_up(v, off, 64);
            if (t >= off) v += n;
        }
        if (t < 16) wScrI[t] = v - orig;
        if (t == 15) scal[0] = v;
    }
    __syncthreads();
    {
        bool need = (matchU[t] == (short)-2);
        u64 m = __ballot(need);
        if (need) {
            int rank = __popcll(m & ((1ull << lane) - 1ull));
            int idx = wScrI[wv] + rank;
            if (idx < BGCAP) bgListSh[idx] = (unsigned short)t;
        }
    }
    __syncthreads();

    // ---- 1b: replay, emit dump-event slots (j-sorted by construction) ----
    {
        const int l = t + 1;
        const int os = occA[t], oe = occA[l];
        const int bs = bSt[t], be = bEnd[l];
        u64 cons = 0;
        for (int o = os; o < oe; o++) {
            int j = occList[o];
            int u = matchU[j];
            if (u < 0) continue;
            int w2 = evAx[j];
            for (int e = bs; e < be; e++) {
                int eIdx = e - bs;
                int p = ldsEnt[e];
                bool consd;
                if (eIdx < 64) consd = (cons >> eIdx) & 1ull;
                else {
                    consd = false;
                    for (int o2 = os; o2 < o; o2++)
                        if ((int)matchU[occList[o2]] == p) { consd = true; break; }
                }
                if (consd) continue;
                if (p == u) { if (eIdx < 64) cons |= 1ull << eIdx; }
                else {
                    if (w2 < EVcap) evPool[w2] = (unsigned short)e;        // slot
                    else if (w2 - EVcap < evCapG) evGlobB[w2 - EVcap] = (unsigned short)p;
                    ++w2;
                }
            }
        }
    }
    __syncthreads();

    // ---- staging: event slots -> contiguous pool right after bg0 ----
    const int bgCnt = min(scal[0], BGCAP);
    {
        const int nStage = min(scal[3], EVcap);
        float2 sc[4]; unsigned short sp[4];
        #pragma unroll
        for (int k = 0; k < 4; k++) {            // constant-index regs (no scratch)
            int i = t + (k << 10);
            if (i < nStage) { int slot = evPool[i]; sp[k] = ldsEnt[slot]; sc[k] = bucketC[slot]; }
        }
        __syncthreads();
        #pragma unroll
        for (int k = 0; k < 4; k++) {
            int i = t + (k << 10);
            if (i < nStage) { ldsEnt[nBg0 + i] = sp[k]; bucketC[nBg0 + i] = sc[k]; }
        }
        if (t < bgCnt) vSteps[t] = ((const float2*)Vb)[bgListSh[t]];   // evPool dead
    }
    __syncthreads();

    // ---- beta: speculative argmins — branch-free linear scans, 1 wave/step ----
    for (int s = wv; s < bgCnt; s += 16) {
        int js = bgListSh[s];
        float2 v = vSteps[s];
        int ne = evAx[js];
        int lim = nBg0 + min(ne, EVcap);
        int tot2 = nBg0 + ne;
        u64 best = ~0ull;
        for (int i = lane; i < tot2; i += 64) {
            float2 c; unsigned p;
            if (i < lim) { c = bucketC[i]; p = ldsEnt[i]; }
            else {
                int ei = i - nBg0 - EVcap;
                if (ei >= evCapG) continue;
                p = evGlobB[ei]; c = ((const float2*)Ub)[p];
            }
            float d = pdist(v.x, v.y, c.x, c.y);
            u64 pk = ((u64)__float_as_uint(d) << 32) | p;
            if (pk < best) best = pk;
        }
        #pragma unroll
        for (int off = 32; off >= 1; off >>= 1) {
            u64 o = __shfl_xor(best, off, 64);
            if (o < best) best = o;
        }
        if (lane == 0) specWin[s] = best;        // bEnd/occA dead -> specWin alias
    }
    __syncthreads();

    // ---- 2c: duplicate-winner check; parallel commit or sequential walk ----
    if (t < bgCnt) {
        u64 w0 = specWin[t];
        if (w0 != ~0ull) {
            unsigned myp = (unsigned)(w0 & 0xFFFFFFFFull);
            for (int s2 = 0; s2 < t; s2++) {
                u64 ws = specWin[s2];
                if (ws != ~0ull && (unsigned)(ws & 0xFFFFFFFFull) == myp) { scal[2] = 1; break; }
            }
        }
    }
    __syncthreads();
    float bgCost = 0.0f;
    if (scal[2] == 0) {
        // all winners distinct -> every speculative winner exact
        if (t < bgCnt) {
            int js = bgListSh[t];
            u64 w0 = specWin[t];
            if (w0 == ~0ull) matchU[js] = -1;
            else {
                matchU[js] = (short)(w0 & 0xFFFFFFFFull);
                costPartial = __fadd_rn(costPartial, __uint_as_float((unsigned)(w0 >> 32)));
            }
        }
    } else if (t < 64) {
        // sequential walk: apply events, O(1) validity check, rare recompute
        int applied = 0;
        for (int s = 0; s < bgCnt; s++) {
            int js = bgListSh[s];
            int target = evAx[js];
            for (int base = applied; base < target; base += 64) {
                int idx = base + t;
                if (idx < target) {
                    int p = (idx < EVcap) ? (int)ldsEnt[nBg0 + idx]
                                          : (int)evGlobB[idx - EVcap];
                    atomicOr(&bgbits[p >> 5], 1u << (p & 31));
                }
            }
            applied = target;
            __threadfence_block();
            u64 w0 = specWin[s];
            if (w0 == ~0ull) {
                if (t == 0) matchU[js] = -1;
            } else {
                int u = (int)(w0 & 0xFFFFFFFFull);
                bool setb = (bgbits[u >> 5] >> (u & 31)) & 1u;
                if (setb) {
                    if (t == 0) {
                        matchU[js] = (short)u;
                        atomicAnd(&bgbits[u >> 5], ~(1u << (u & 31)));
                        bgCost = __fadd_rn(bgCost, __uint_as_float((unsigned)(w0 >> 32)));
                    }
                } else {
                    float2 v = vSteps[s];
                    u64 best = ~0ull;
                    #pragma unroll
                    for (int i = 0; i < 2; i++) {
                        int wi = t * 2 + i;
                        unsigned bits = bgbits[wi];
                        int pb = wi << 5;
                        while (bits) {
                            int bpos = __builtin_ctz(bits);
                            bits &= bits - 1;
                            int p = pb + bpos;
                            float2 uu = ((const float2*)Ub)[p];
                            float d = pdist(v.x, v.y, uu.x, uu.y);
                            u64 pk = ((u64)__float_as_uint(d) << 32) | (unsigned)p;
                            if (pk < best) best = pk;
                        }
                    }
                    #pragma unroll
                    for (int off = 32; off >= 1; off >>= 1) {
                        u64 o = __shfl_xor(best, off, 64);
                        if (o < best) best = o;
                    }
                    if (t == 0) {
                        if (best != ~0ull) {
                            int u2 = (int)(best & 0xFFFFFFFFull);
                            matchU[js] = (short)u2;
                            atomicAnd(&bgbits[u2 >> 5], ~(1u << (u2 & 31)));
                            bgCost = __fadd_rn(bgCost, __uint_as_float((unsigned)(best >> 32)));
                        } else matchU[js] = -1;
                    }
                }
                __threadfence_block();
            }
        }
    }
    __syncthreads();

    // ---- epilogue: cost reduction + outputs ----
    {
        float cp = costPartial;
        #pragma unroll
        for (int off = 32; off >= 1; off >>= 1) cp += __shfl_xor(cp, off, 64);
        if (lane == 0) wScrF[wv] = cp;
    }
    __syncthreads();
    if (t == 0) {
        float tot = bgCost;
        for (int i = 0; i < 16; ++i) tot = __fadd_rn(tot, wScrF[i]);
        out[(size_t)2 * B * NGT + b] = tot;
    }
    {
        int u = matchU[t];
        out[(size_t)b * NGT + t] = (float)u;
        out[(size_t)B * NGT + (size_t)b * NGT + t] = (u >= 0) ? (float)t : -1.0f;
    }
}

extern "C" void kernel_launch(void* const* d_in, const int* in_sizes, int n_in,
                              void* d_out, int out_size, void* d_ws, size_t ws_size,
                              hipStream_t stream) {
    const float* pred   = (const float*)d_in[0];
    const float* coords = (const float*)d_in[1];
    const int*   keys   = (const int*)d_in[2];
    const int*   masks  = (const int*)d_in[3];
    float* out = (float*)d_out;
    int B = in_sizes[2] / NGT;   // 8
    int evCapG = (int)((ws_size / (size_t)B) / sizeof(unsigned short));
    matcher_kernel<<<B, 1024, 0, stream>>>(pred, coords, keys, masks, out,
                                           (unsigned short*)d_ws, evCapG, B);
}

// Round 7
// 165.764 us; speedup vs baseline: 1.8866x; 1.1194x over previous
//
#include <hip/hip_runtime.h>
#include <stdint.h>

// Problem constants: B=8, P=4096, N=1024, H=W=1024, labels 0..1024
#define PPTS 4096
#define NGT  1024
#define HH   1024
#define WW   1024
#define EVPOOL_CAP 3072   // LDS event-slot pool; first-dump events ~1900 < cap
#define BGCAP 160         // max bg steps (E[m] ~65)

typedef unsigned long long u64;

__device__ __forceinline__ float pdist(float vx, float vy, float ux, float uy) {
    float dx = __fsub_rn(vx, ux);
    float dy = __fsub_rn(vy, uy);
    return __fsqrt_rn(__fadd_rn(__fmul_rn(dx, dx), __fmul_rn(dy, dy)));
}

// One block per batch.
//  Key identity: every present-bucket entry is bg-dumped exactly at its
//  label's FIRST occurrence step j1 (except that step's winner); later dumps
//  are set-idempotent. So event counts (bucket-1) are known BEFORE matching,
//  and the event-offset scan folds into the quad-packed phase-C scan.
//  A-B : zero, histograms, firstOcc atomicMin, mask gather, U in regs.
//  C   : quad-packed u64 exclusive scan: bg<<48 | present<<32 | ev<<16 | occ
//        -> bg-first bucket starts, occ starts, per-step event offsets evAx.
//  D   : scatter coords+ids (bg0 list = [0,nBg0) for free), occ lists.
//  1a  : one thread per label: inside-match chain; at first occurrence also
//        emits its dump events (bucket minus winner) at evAx[j1].
//  stg : event slots -> contiguous staged pool at [nBg0, nBg0+totEv).
//  beta: speculative per-step argmin = contiguous scan of [0, nBg0+ne),
//        one wave per step.
//  2c  : dup-check -> parallel commit (exact) or sequential fallback walk.
__global__ __launch_bounds__(1024) void matcher_kernel(
    const float* __restrict__ pred,    // [B,P,2]
    const float* __restrict__ coords,  // [B,N,2]
    const int*   __restrict__ keys,    // [B,N]
    const int*   __restrict__ masks,   // [B,H,W]
    float* __restrict__ out,           // [B*N src][B*N tgt][B total]
    unsigned short* __restrict__ evGlobAll, int evCapG, int B)
{
    __shared__ __align__(16) char regU[32768];          // bucketC f2[4096] (bg0 + staged ev)
    __shared__ __align__(8)  char regE[8192];           // ldsEnt u16[4096] (bg0 + staged ev)
    __shared__ __align__(8)  char regB[8200];           // bEnd[1025]+occA[1025] -> specWin u64[BGCAP]
    __shared__ __align__(8)  char regP[2 * EVPOOL_CAP]; // firstOcc i32[1025] -> evPool u16 -> vSteps
    __shared__ __align__(4)  char regS[384];            // present u32[33] -> bgListSh u16[BGCAP]
    __shared__ u64            wScr64[16];
    __shared__ u64            sTot;
    __shared__ unsigned short evAx[1024];               // per-step exclusive event offsets
    __shared__ unsigned short occList[NGT];
    __shared__ short          matchU[NGT];
    __shared__ unsigned       bgbits[PPTS / 32];
    __shared__ unsigned short bSt[1024];
    __shared__ int            scal[4];                  // 0:bgCnt 2:dupFlag

    float2*         bucketC  = (float2*)regU;
    unsigned short* ldsEnt   = (unsigned short*)regE;
    int*            bEnd     = (int*)regB;
    int*            occA     = ((int*)regB) + 1025;
    u64*            specWin  = (u64*)regB;
    int*            firstOcc = (int*)regP;              // dead after C
    unsigned short* evPool   = (unsigned short*)regP;   // 1a..staging
    float2*         vSteps   = (float2*)regP;           // staging..end
    unsigned*       present  = (unsigned*)regS;
    unsigned short* bgListSh = (unsigned short*)regS;
    int*   wScrI = (int*)wScr64;
    float* wScrF = (float*)wScr64;

    const int b = blockIdx.x;
    const int t = threadIdx.x;
    const int lane = t & 63, wv = t >> 6;
    const float* Ub = pred   + (size_t)b * PPTS * 2;
    const float* Vb = coords + (size_t)b * NGT * 2;
    const int*   Kb = keys   + (size_t)b * NGT;
    const int*   Mb = masks  + (size_t)b * HH * WW;
    unsigned short* evGlobB = evGlobAll + (size_t)b * (size_t)evCapG;

    // ---- A: zero ----
    bEnd[t] = 0; occA[t] = 0; firstOcc[t] = 0x7FFFFFFF;
    if (t == 0) { bEnd[1024] = 0; occA[1024] = 0; firstOcc[1024] = 0x7FFFFFFF;
                  scal[0] = 0; scal[2] = 0; }
    if (t < PPTS / 32) bgbits[t] = 0;
    if (t < 33) present[t] = 0;
    __syncthreads();

    // ---- B: histograms + firstOcc + mask gather; U coords stay in regs ----
    const int k1 = Kb[t] + 1;                    // label of step j=t, in [1,1024]
    atomicOr(&present[k1 >> 5], 1u << (k1 & 31));
    atomicAdd(&occA[k1], 1);
    atomicMin(&firstOcc[k1], t);
    int lab[4]; float2 up[4];
    #pragma unroll
    for (int i = 0; i < 4; i++) {
        int p = t + (i << 10);
        float2 u = ((const float2*)Ub)[p];
        up[i] = u;
        int xi = (int)rintf(__fmul_rn(u.x, 1024.0f));  // rintf == jnp.round (half-even)
        int yi = (int)rintf(__fmul_rn(u.y, 1024.0f));
        xi = min(max(xi, 0), HH - 1);
        yi = min(max(yi, 0), WW - 1);
        lab[i] = Mb[xi * WW + yi];
        atomicAdd(&bEnd[lab[i]], 1);
    }
    __syncthreads();

    // ---- C: quad-packed exclusive scan (bg<<48 | pr<<32 | ev<<16 | occ) ----
    {
        // label-domain reads (label = t)
        int c0 = bEnd[t], o0 = occA[t];
        bool pr0 = (present[t >> 5] >> (t & 31)) & 1u;
        // step-domain reads (step = t, its label = k1)
        int bCnt = bEnd[k1];
        int fo   = firstOcc[k1];
        int evc  = (fo == t && bCnt > 0) ? (bCnt - 1) : 0;
        u64 myv = (pr0 ? ((u64)(unsigned)c0 << 32) : ((u64)(unsigned)c0 << 48))
                  | ((u64)(unsigned)evc << 16) | (u64)(unsigned)o0;
        u64 add1 = 0; bool pr1 = false;
        if (t == 1023) {                          // fold label 1024 (no step 1024)
            int c1 = bEnd[1024], o1 = occA[1024];
            pr1 = present[32] & 1u;
            add1 = (pr1 ? ((u64)(unsigned)c1 << 32) : ((u64)(unsigned)c1 << 48))
                   | (u64)(unsigned)o1;
        }
        u64 tot = myv + add1;
        u64 inc = tot;
        #pragma unroll
        for (int off = 1; off < 64; off <<= 1) {
            u64 n = __shfl_up(inc, off, 64);
            if (lane >= off) inc += n;
        }
        if (lane == 63) wScr64[wv] = inc;
        __syncthreads();
        if (t < 16) {
            u64 v = wScr64[t], inc2 = v;
            #pragma unroll
            for (int off = 1; off < 16; off <<= 1) {
                u64 n = __shfl_up(inc2, off, 64);
                if (t >= off) inc2 += n;
            }
            wScr64[t] = inc2 - v;
            if (t == 15) sTot = inc2;
        }
        __syncthreads();
        u64 excl = wScr64[wv] + inc - tot;
        int nBg0v = (int)(sTot >> 48);
        int bgS = (int)(excl >> 48);
        int prS = (int)((excl >> 32) & 0xFFFF);
        int evS = (int)((excl >> 16) & 0xFFFF);
        int ocS = (int)(excl & 0xFFFF);
        int start0 = pr0 ? (nBg0v + prS) : bgS;
        bEnd[t] = start0;                         // scatter cursor
        occA[t] = ocS;
        evAx[t] = (unsigned short)evS;            // events from steps < t
        if (t >= 1) bSt[t - 1] = (unsigned short)start0;
        if (t == 1023) {
            u64 ex1 = excl + myv;
            int bgS1 = (int)(ex1 >> 48);
            int prS1 = (int)((ex1 >> 32) & 0xFFFF);
            int start1 = pr1 ? (nBg0v + prS1) : bgS1;
            bEnd[1024] = start1; occA[1024] = (int)(ex1 & 0xFFFF);
            bSt[1023] = (unsigned short)start1;
        }
    }
    __syncthreads();
    const int nBg0  = (int)(sTot >> 48);
    const int totEv = (int)((sTot >> 16) & 0xFFFF);
    const int EVcap = min(EVPOOL_CAP, PPTS - nBg0);

    // ---- D: scatter coords+ids (bg labels land in [0,nBg0)), occ lists ----
    #pragma unroll
    for (int i = 0; i < 4; i++) {
        int p = t + (i << 10);
        int slot = atomicAdd(&bEnd[lab[i]], 1);
        ldsEnt[slot] = (unsigned short)p;
        bucketC[slot] = up[i];
        if (!((present[lab[i] >> 5] >> (lab[i] & 31)) & 1u))
            atomicOr(&bgbits[p >> 5], 1u << (p & 31));   // fallback path only
    }
    {
        int slot = atomicAdd(&occA[k1], 1);
        occList[slot] = (unsigned short)t;
    }
    __syncthreads();

    // ---- 1a: per-label inside-match chains + first-occurrence event emission ----
    float costPartial = 0.0f;
    {
        const int l = t + 1;
        const int os = occA[t], oe = occA[l];
        for (int i = os + 1; i < oe; i++) {          // sort occurrences ascending
            unsigned short v = occList[i];
            int k = i - 1;
            while (k >= os && occList[k] > v) { occList[k + 1] = occList[k]; k--; }
            occList[k + 1] = v;
        }
        const int bs = bSt[t], be = bEnd[l];
        u64 cons = 0;
        for (int o = os; o < oe; o++) {
            int j = occList[o];
            float2 v = ((const float2*)Vb)[j];
            u64 best = ~0ull;
            int avail = 0;
            for (int e = bs; e < be; e++) {
                int eIdx = e - bs;
                int p = ldsEnt[e];
                bool consd;
                if (eIdx < 64) consd = (cons >> eIdx) & 1ull;
                else {                                // exact fallback (never in practice)
                    consd = false;
                    for (int o2 = os; o2 < o; o2++)
                        if ((int)matchU[occList[o2]] == p) { consd = true; break; }
                }
                if (consd) continue;
                avail++;
                float2 u = bucketC[e];
                float d = pdist(v.x, v.y, u.x, u.y);
                u64 pk = ((u64)__float_as_uint(d) << 24) | ((u64)(unsigned)p << 12)
                         | (u64)(unsigned)eIdx;
                if (pk < best) best = pk;
            }
            if (avail > 0) {
                int eW = (int)(best & 0xFFFull);
                int pW = (int)((best >> 12) & 0xFFFull);
                costPartial = __fadd_rn(costPartial, __uint_as_float((unsigned)(best >> 24)));
                matchU[j] = (short)pW;
                if (eW < 64) cons |= 1ull << eW;
                if (o == os) {
                    // first occurrence: emit all non-winner entries at evAx[j]
                    int base = evAx[j], w3 = 0;
                    for (int e = bs; e < be; e++) {
                        if (e - bs == eW) continue;
                        int idx = base + w3;
                        if (idx < EVcap) evPool[idx] = (unsigned short)e;       // slot
                        else if (idx - EVcap < evCapG) evGlobB[idx - EVcap] = ldsEnt[e]; // pid
                        w3++;
                    }
                }
            } else {
                matchU[j] = -2;
            }
        }
    }
    __syncthreads();

    // ---- bg-step list compaction (ascending j) ----
    {
        bool need = (matchU[t] == (short)-2);
        u64 m = __ballot(need);
        if (lane == 0) wScrI[wv] = __popcll(m);
    }
    __syncthreads();
    if (t < 64) {
        int orig = (t < 16) ? wScrI[t] : 0;
        int v = orig;
        #pragma unroll
        for (int off = 1; off <= 8; off <<= 1) {
            int n = __shfl_up(v, off, 64);
            if (t >= off) v += n;
        }
        if (t < 16) wScrI[t] = v - orig;
        if (t == 15) scal[0] = v;
    }
    __syncthreads();
    {
        bool need = (matchU[t] == (short)-2);
        u64 m = __ballot(need);
        if (need) {
            int rank = __popcll(m & ((1ull << lane) - 1ull));
            int idx = wScrI[wv] + rank;
            if (idx < BGCAP) bgListSh[idx] = (unsigned short)t;
        }
    }
    __syncthreads();

    // ---- staging: event slots -> contiguous pool right after bg0 ----
    const int bgCnt = min(scal[0], BGCAP);
    {
        const int nStage = min(totEv, EVcap);
        float2 sc[4]; unsigned short sp[4];
        #pragma unroll
        for (int k = 0; k < 4; k++) {            // constant-index regs (no scratch)
            int i = t + (k << 10);
            if (i < nStage) { int slot = evPool[i]; sp[k] = ldsEnt[slot]; sc[k] = bucketC[slot]; }
        }
        __syncthreads();
        #pragma unroll
        for (int k = 0; k < 4; k++) {
            int i = t + (k << 10);
            if (i < nStage) { ldsEnt[nBg0 + i] = sp[k]; bucketC[nBg0 + i] = sc[k]; }
        }
        if (t < bgCnt) vSteps[t] = ((const float2*)Vb)[bgListSh[t]];   // evPool dead
    }
    __syncthreads();

    // ---- beta: speculative argmins — contiguous LDS scans, 1 wave/step ----
    for (int s = wv; s < bgCnt; s += 16) {
        int js = bgListSh[s];
        float2 v = vSteps[s];
        int ne = evAx[js];
        int lim = nBg0 + min(ne, EVcap);
        u64 best = ~0ull;
        for (int i = lane; i < lim; i += 64) {   // pure-LDS, branch-free
            float2 c = bucketC[i];
            unsigned p = ldsEnt[i];
            float d = pdist(v.x, v.y, c.x, c.y);
            u64 pk = ((u64)__float_as_uint(d) << 32) | p;
            if (pk < best) best = pk;
        }
        for (int ei = EVcap + lane; ei < ne; ei += 64) {   // global spill tail (rare)
            if (ei - EVcap >= evCapG) break;
            unsigned p = evGlobB[ei - EVcap];
            float2 c = ((const float2*)Ub)[p];
            float d = pdist(v.x, v.y, c.x, c.y);
            u64 pk = ((u64)__float_as_uint(d) << 32) | p;
            if (pk < best) best = pk;
        }
        #pragma unroll
        for (int off = 32; off >= 1; off >>= 1) {
            u64 o = __shfl_xor(best, off, 64);
            if (o < best) best = o;
        }
        if (lane == 0) specWin[s] = best;        // bEnd/occA dead -> specWin alias
    }
    __syncthreads();

    // ---- 2c: duplicate-winner check; parallel commit or sequential walk ----
    if (t < bgCnt) {
        u64 w0 = specWin[t];
        if (w0 != ~0ull) {
            unsigned myp = (unsigned)(w0 & 0xFFFFFFFFull);
            for (int s2 = 0; s2 < t; s2++) {
                u64 ws = specWin[s2];
                if (ws != ~0ull && (unsigned)(ws & 0xFFFFFFFFull) == myp) { scal[2] = 1; break; }
            }
        }
    }
    __syncthreads();
    float bgCost = 0.0f;
    if (scal[2] == 0) {
        // all winners distinct -> every speculative winner exact
        if (t < bgCnt) {
            int js = bgListSh[t];
            u64 w0 = specWin[t];
            if (w0 == ~0ull) matchU[js] = -1;
            else {
                matchU[js] = (short)(w0 & 0xFFFFFFFFull);
                costPartial = __fadd_rn(costPartial, __uint_as_float((unsigned)(w0 >> 32)));
            }
        }
    } else if (t < 64) {
        // sequential walk: apply events, O(1) validity check, rare recompute
        int applied = 0;
        for (int s = 0; s < bgCnt; s++) {
            int js = bgListSh[s];
            int target = evAx[js];
            for (int base = applied; base < target; base += 64) {
                int idx = base + t;
                if (idx < target) {
                    int p = (idx < EVcap) ? (int)ldsEnt[nBg0 + idx]
                                          : (int)evGlobB[idx - EVcap];
                    atomicOr(&bgbits[p >> 5], 1u << (p & 31));
                }
            }
            applied = target;
            __threadfence_block();
            u64 w0 = specWin[s];
            if (w0 == ~0ull) {
                if (t == 0) matchU[js] = -1;
            } else {
                int u = (int)(w0 & 0xFFFFFFFFull);
                bool setb = (bgbits[u >> 5] >> (u & 31)) & 1u;
                if (setb) {
                    if (t == 0) {
                        matchU[js] = (short)u;
                        atomicAnd(&bgbits[u >> 5], ~(1u << (u & 31)));
                        bgCost = __fadd_rn(bgCost, __uint_as_float((unsigned)(w0 >> 32)));
                    }
                } else {
                    float2 v = vSteps[s];
                    u64 best = ~0ull;
                    #pragma unroll
                    for (int i = 0; i < 2; i++) {
                        int wi = t * 2 + i;
                        unsigned bits = bgbits[wi];
                        int pb = wi << 5;
                        while (bits) {
                            int bpos = __builtin_ctz(bits);
                            bits &= bits - 1;
                            int p = pb + bpos;
                            float2 uu = ((const float2*)Ub)[p];
                            float d = pdist(v.x, v.y, uu.x, uu.y);
                            u64 pk = ((u64)__float_as_uint(d) << 32) | (unsigned)p;
                            if (pk < best) best = pk;
                        }
                    }
                    #pragma unroll
                    for (int off = 32; off >= 1; off >>= 1) {
                        u64 o = __shfl_xor(best, off, 64);
                        if (o < best) best = o;
                    }
                    if (t == 0) {
                        if (best != ~0ull) {
                            int u2 = (int)(best & 0xFFFFFFFFull);
                            matchU[js] = (short)u2;
                            atomicAnd(&bgbits[u2 >> 5], ~(1u << (u2 & 31)));
                            bgCost = __fadd_rn(bgCost, __uint_as_float((unsigned)(best >> 32)));
                        } else matchU[js] = -1;
                    }
                }
                __threadfence_block();
            }
        }
    }
    __syncthreads();

    // ---- epilogue: cost reduction + outputs ----
    {
        float cp = costPartial;
        #pragma unroll
        for (int off = 32; off >= 1; off >>= 1) cp += __shfl_xor(cp, off, 64);
        if (lane == 0) wScrF[wv] = cp;
    }
    __syncthreads();
    if (t == 0) {
        float tot = bgCost;
        for (int i = 0; i < 16; ++i) tot = __fadd_rn(tot, wScrF[i]);
        out[(size_t)2 * B * NGT + b] = tot;
    }
    {
        int u = matchU[t];
        out[(size_t)b * NGT + t] = (float)u;
        out[(size_t)B * NGT + (size_t)b * NGT + t] = (u >= 0) ? (float)t : -1.0f;
    }
}

extern "C" void kernel_launch(void* const* d_in, const int* in_sizes, int n_in,
                              void* d_out, int out_size, void* d_ws, size_t ws_size,
                              hipStream_t stream) {
    const float* pred   = (const float*)d_in[0];
    const float* coords = (const float*)d_in[1];
    const int*   keys   = (const int*)d_in[2];
    const int*   masks  = (const int*)d_in[3];
    float* out = (float*)d_out;
    int B = in_sizes[2] / NGT;   // 8
    int evCapG = (int)((ws_size / (size_t)B) / sizeof(unsigned short));
    matcher_kernel<<<B, 1024, 0, stream>>>(pred, coords, keys, masks, out,
                                           (unsigned short*)d_ws, evCapG, B);
}

// Round 8
// 165.209 us; speedup vs baseline: 1.8930x; 1.0034x over previous
//
#include <hip/hip_runtime.h>
#include <stdint.h>

// Problem constants: B=8, P=4096, N=1024, H=W=1024, labels 0..1024
#define PPTS 4096
#define NGT  1024
#define HH   1024
#define WW   1024
#define EVPOOL_CAP 3072   // LDS event-slot pool; first-dump events ~1900 < cap
#define BGCAP 160         // max bg steps (E[m] ~65)
#define RB 12             // register-bucket cap in 1a (P[bucket>12] ~ 4e-4)

// workspace layout (per batch): hist = 3136 ints (bucket[1025], occ[1025],
// fMax[1025], present u32[33]); labels u16[4096]; spill u16[2048]
#define HIST_I32   3136
#define HIST_BYTES (8 * HIST_I32 * 4)          // 100352
#define LAB_OFF    HIST_BYTES
#define SPILL_OFF  (LAB_OFF + 8 * PPTS * 2)    // 165888
#define SPILL_CAP  2048
#define WS_NEED    (SPILL_OFF + 8 * SPILL_CAP * 2)

typedef unsigned long long u64;

__device__ __forceinline__ float pdist(float vx, float vy, float ux, float uy) {
    float dx = __fsub_rn(vx, ux);
    float dy = __fsub_rn(vy, uy);
    return __fsqrt_rn(__fadd_rn(__fmul_rn(dx, dx), __fmul_rn(dy, dy)));
}

// K1: 4 blocks per batch — labels (random mask gather) + global histograms.
__global__ __launch_bounds__(1024) void label_kernel(
    const float* __restrict__ pred, const int* __restrict__ keys,
    const int* __restrict__ masks, int* __restrict__ hist,
    unsigned short* __restrict__ labs)
{
    const int blk = blockIdx.x, b = blk >> 2, sb = blk & 3;
    const int t = threadIdx.x;
    const int p = (sb << 10) + t;
    const float2* Ub2 = (const float2*)(pred + (size_t)b * PPTS * 2);
    const int* Mb = masks + (size_t)b * HH * WW;
    int* H = hist + (size_t)b * HIST_I32;

    float2 u = Ub2[p];
    int xi = (int)rintf(__fmul_rn(u.x, 1024.0f));   // rintf == jnp.round (half-even)
    int yi = (int)rintf(__fmul_rn(u.y, 1024.0f));
    xi = min(max(xi, 0), HH - 1);
    yi = min(max(yi, 0), WW - 1);
    int lab = Mb[xi * WW + yi];
    labs[(size_t)b * PPTS + p] = (unsigned short)lab;
    atomicAdd(&H[lab], 1);
    if (sb == 0) {
        int k1 = keys[(size_t)b * NGT + t] + 1;     // label of step t
        atomicAdd(&H[1025 + k1], 1);
        atomicMax(&H[2050 + k1], 1023 - t);         // firstOcc = 1023 - max
        atomicOr((unsigned*)&H[3075 + (k1 >> 5)], 1u << (k1 & 31));
    }
}

// K2: one block per batch. Loads hist/labels (useWs) or builds them (mono).
__global__ __launch_bounds__(1024) void matcher_kernel(
    const float* __restrict__ pred,    // [B,P,2]
    const float* __restrict__ coords,  // [B,N,2]
    const int*   __restrict__ keys,    // [B,N]
    const int*   __restrict__ masks,   // [B,H,W] (mono path only)
    float* __restrict__ out,           // [B*N src][B*N tgt][B total]
    const int* __restrict__ hist, const unsigned short* __restrict__ labs,
    unsigned short* __restrict__ spill, int useWs, int B)
{
    __shared__ __align__(16) char regU[32768];          // bucketC f2[4096] (bg0 + staged ev)
    __shared__ __align__(8)  char regE[8192];           // ldsEnt u16[4096]
    __shared__ __align__(8)  char regB[8200];           // bEnd+occA -> specWin u64[BGCAP]
    __shared__ __align__(8)  char regP[2 * EVPOOL_CAP]; // firstOcc i32 -> evPool u16 -> vSteps
    __shared__ __align__(4)  char regS[384];            // present u32[33] -> bgListSh u16[BGCAP]
    __shared__ u64            wScr64[16];
    __shared__ u64            sTot;
    __shared__ unsigned short evAx[1024];
    __shared__ unsigned short occList[NGT];
    __shared__ short          matchU[NGT];
    __shared__ unsigned       bgbits[PPTS / 32];
    __shared__ unsigned short bSt[1024];
    __shared__ int            scal[4];                  // 0:bgCnt 2:dupFlag

    float2*         bucketC  = (float2*)regU;
    unsigned short* ldsEnt   = (unsigned short*)regE;
    int*            bEnd     = (int*)regB;
    int*            occA     = ((int*)regB) + 1025;
    u64*            specWin  = (u64*)regB;
    int*            firstOcc = (int*)regP;
    unsigned short* evPool   = (unsigned short*)regP;
    float2*         vSteps   = (float2*)regP;
    unsigned*       present  = (unsigned*)regS;
    unsigned short* bgListSh = (unsigned short*)regS;
    int*   wScrI = (int*)wScr64;
    float* wScrF = (float*)wScr64;

    const int b = blockIdx.x;
    const int t = threadIdx.x;
    const int lane = t & 63, wv = t >> 6;
    const float* Ub = pred   + (size_t)b * PPTS * 2;
    const float2* Ub2 = (const float2*)Ub;
    const float* Vb = coords + (size_t)b * NGT * 2;
    const int*   Kb = keys   + (size_t)b * NGT;
    unsigned short* evSpillB = spill + (size_t)b * SPILL_CAP;
    const int spillCap = useWs ? SPILL_CAP : 0;

    // ---- A/B: state init + labels & histograms (load or build) ----
    if (t < PPTS / 32) bgbits[t] = 0;
    if (t == 0) { scal[0] = 0; scal[2] = 0; }
    const int k1 = Kb[t] + 1;                    // label of step j=t, in [1,1024]
    int lab[4]; float2 up[4];
    #pragma unroll
    for (int i = 0; i < 4; i++) up[i] = Ub2[t + (i << 10)];
    if (useWs) {
        const int* H = hist + (size_t)b * HIST_I32;
        bEnd[t] = H[t]; occA[t] = H[1025 + t]; firstOcc[t] = 1023 - H[2050 + t];
        if (t == 0) { bEnd[1024] = H[1024]; occA[1024] = H[2049];
                      firstOcc[1024] = 1023 - H[3074]; }
        if (t < 33) present[t] = ((const unsigned*)H)[3075 + t];
        const unsigned short* Lb = labs + (size_t)b * PPTS;
        #pragma unroll
        for (int i = 0; i < 4; i++) lab[i] = Lb[t + (i << 10)];
    } else {
        bEnd[t] = 0; occA[t] = 0; firstOcc[t] = 0x7FFFFFFF;
        if (t == 0) { bEnd[1024] = 0; occA[1024] = 0; firstOcc[1024] = 0x7FFFFFFF; }
        if (t < 33) present[t] = 0;
        __syncthreads();
        const int* Mb = masks + (size_t)b * HH * WW;
        atomicOr(&present[k1 >> 5], 1u << (k1 & 31));
        atomicAdd(&occA[k1], 1);
        atomicMin(&firstOcc[k1], t);
        #pragma unroll
        for (int i = 0; i < 4; i++) {
            float2 u = up[i];
            int xi = (int)rintf(__fmul_rn(u.x, 1024.0f));
            int yi = (int)rintf(__fmul_rn(u.y, 1024.0f));
            xi = min(max(xi, 0), HH - 1);
            yi = min(max(yi, 0), WW - 1);
            lab[i] = Mb[xi * WW + yi];
            atomicAdd(&bEnd[lab[i]], 1);
        }
    }
    __syncthreads();

    // ---- C: quad-packed exclusive scan (bg<<48 | pr<<32 | ev<<16 | occ) ----
    {
        int c0 = bEnd[t], o0 = occA[t];
        bool pr0 = (present[t >> 5] >> (t & 31)) & 1u;
        int bCnt = bEnd[k1];
        int fo   = firstOcc[k1];
        int evc  = (fo == t && bCnt > 0) ? (bCnt - 1) : 0;
        u64 myv = (pr0 ? ((u64)(unsigned)c0 << 32) : ((u64)(unsigned)c0 << 48))
                  | ((u64)(unsigned)evc << 16) | (u64)(unsigned)o0;
        u64 add1 = 0; bool pr1 = false;
        if (t == 1023) {                          // fold label 1024 (no step 1024)
            int c1 = bEnd[1024], o1 = occA[1024];
            pr1 = present[32] & 1u;
            add1 = (pr1 ? ((u64)(unsigned)c1 << 32) : ((u64)(unsigned)c1 << 48))
                   | (u64)(unsigned)o1;
        }
        u64 tot = myv + add1;
        u64 inc = tot;
        #pragma unroll
        for (int off = 1; off < 64; off <<= 1) {
            u64 n = __shfl_up(inc, off, 64);
            if (lane >= off) inc += n;
        }
        if (lane == 63) wScr64[wv] = inc;
        __syncthreads();
        if (t < 16) {
            u64 v = wScr64[t], inc2 = v;
            #pragma unroll
            for (int off = 1; off < 16; off <<= 1) {
                u64 n = __shfl_up(inc2, off, 64);
                if (t >= off) inc2 += n;
            }
            wScr64[t] = inc2 - v;
            if (t == 15) sTot = inc2;
        }
        __syncthreads();
        u64 excl = wScr64[wv] + inc - tot;
        int nBg0v = (int)(sTot >> 48);
        int bgS = (int)(excl >> 48);
        int prS = (int)((excl >> 32) & 0xFFFF);
        int evS = (int)((excl >> 16) & 0xFFFF);
        int ocS = (int)(excl & 0xFFFF);
        int start0 = pr0 ? (nBg0v + prS) : bgS;
        bEnd[t] = start0;
        occA[t] = ocS;
        evAx[t] = (unsigned short)evS;
        if (t >= 1) bSt[t - 1] = (unsigned short)start0;
        if (t == 1023) {
            u64 ex1 = excl + myv;
            int bgS1 = (int)(ex1 >> 48);
            int prS1 = (int)((ex1 >> 32) & 0xFFFF);
            int start1 = pr1 ? (nBg0v + prS1) : bgS1;
            bEnd[1024] = start1; occA[1024] = (int)(ex1 & 0xFFFF);
            bSt[1023] = (unsigned short)start1;
        }
    }
    __syncthreads();
    const int nBg0  = (int)(sTot >> 48);
    const int totEv = (int)((sTot >> 16) & 0xFFFF);
    const int EVcap = min(EVPOOL_CAP, PPTS - nBg0);

    // ---- D: scatter coords+ids (bg labels land in [0,nBg0)), occ lists ----
    #pragma unroll
    for (int i = 0; i < 4; i++) {
        int p = t + (i << 10);
        int slot = atomicAdd(&bEnd[lab[i]], 1);
        ldsEnt[slot] = (unsigned short)p;
        bucketC[slot] = up[i];
        if (!((present[lab[i] >> 5] >> (lab[i] & 31)) & 1u))
            atomicOr(&bgbits[p >> 5], 1u << (p & 31));   // fallback path only
    }
    {
        int slot = atomicAdd(&occA[k1], 1);
        occList[slot] = (unsigned short)t;
    }
    __syncthreads();

    // ---- 1a: per-label inside-match chains (register-resident buckets) ----
    float costPartial = 0.0f;
    {
        const int l = t + 1;
        const int os = occA[t], oe = occA[l];
        for (int i = os + 1; i < oe; i++) {          // sort occurrences ascending
            unsigned short v = occList[i];
            int k = i - 1;
            while (k >= os && occList[k] > v) { occList[k + 1] = occList[k]; k--; }
            occList[k + 1] = v;
        }
        const int bs = bSt[t], be = bEnd[l];
        const int bn = be - bs;
        if (oe > os && bn > 0 && bn <= RB) {
            // fast path: bucket in registers, argmin is pure predicated VALU
            float rcx[RB], rcy[RB]; int rp[RB];
            #pragma unroll
            for (int k = 0; k < RB; k++)
                if (k < bn) { float2 c = bucketC[bs + k]; rcx[k] = c.x; rcy[k] = c.y;
                              rp[k] = ldsEnt[bs + k]; }
            unsigned cons = 0;
            for (int o = os; o < oe; o++) {
                int j = occList[o];
                float2 v = ((const float2*)Vb)[j];
                u64 best = ~0ull;
                #pragma unroll
                for (int k = 0; k < RB; k++) {
                    if (k < bn && !((cons >> k) & 1u)) {
                        float d = pdist(v.x, v.y, rcx[k], rcy[k]);
                        u64 pk = ((u64)__float_as_uint(d) << 24)
                                 | ((u64)(unsigned)rp[k] << 12) | (u64)(unsigned)k;
                        if (pk < best) best = pk;
                    }
                }
                if (best != ~0ull) {
                    int eW = (int)(best & 0xFFFull);
                    matchU[j] = (short)((best >> 12) & 0xFFFull);
                    costPartial = __fadd_rn(costPartial,
                                            __uint_as_float((unsigned)(best >> 24)));
                    cons |= 1u << eW;
                    if (o == os) {                    // first occurrence: emit dumps
                        int base = evAx[j];
                        #pragma unroll
                        for (int k = 0; k < RB; k++) {
                            if (k < bn && k != eW) {
                                int idx = base + k - (k > eW ? 1 : 0);
                                if (idx < EVcap) evPool[idx] = (unsigned short)(bs + k);
                                else if (idx - EVcap < spillCap)
                                    evSpillB[idx - EVcap] = (unsigned short)rp[k];
                            }
                        }
                    }
                } else matchU[j] = -2;
            }
        } else if (oe > os) {
            // generic path: big buckets (rare) or empty bucket
            u64 cons = 0;
            for (int o = os; o < oe; o++) {
                int j = occList[o];
                float2 v = ((const float2*)Vb)[j];
                u64 best = ~0ull;
                int avail = 0;
                for (int e = bs; e < be; e++) {
                    int eIdx = e - bs;
                    int p = ldsEnt[e];
                    bool consd;
                    if (eIdx < 64) consd = (cons >> eIdx) & 1ull;
                    else {
                        consd = false;
                        for (int o2 = os; o2 < o; o2++)
                            if ((int)matchU[occList[o2]] == p) { consd = true; break; }
                    }
                    if (consd) continue;
                    avail++;
                    float2 u = bucketC[e];
                    float d = pdist(v.x, v.y, u.x, u.y);
                    u64 pk = ((u64)__float_as_uint(d) << 24) | ((u64)(unsigned)p << 12)
                             | (u64)(unsigned)eIdx;
                    if (pk < best) best = pk;
                }
                if (avail > 0) {
                    int eW = (int)(best & 0xFFFull);
                    matchU[j] = (short)((best >> 12) & 0xFFFull);
                    costPartial = __fadd_rn(costPartial,
                                            __uint_as_float((unsigned)(best >> 24)));
                    if (eW < 64) cons |= 1ull << eW;
                    if (o == os) {
                        int base = evAx[j], w3 = 0;
                        for (int e = bs; e < be; e++) {
                            if (e - bs == eW) continue;
                            int idx = base + w3;
                            if (idx < EVcap) evPool[idx] = (unsigned short)e;
                            else if (idx - EVcap < spillCap)
                                evSpillB[idx - EVcap] = ldsEnt[e];
                            w3++;
                        }
                    }
                } else matchU[j] = -2;
            }
        }
    }
    __syncthreads();

    // ---- bg-step list compaction (ascending j) ----
    {
        bool need = (matchU[t] == (short)-2);
        u64 m = __ballot(need);
        if (lane == 0) wScrI[wv] = __popcll(m);
    }
    __syncthreads();
    if (t < 64) {
        int orig = (t < 16) ? wScrI[t] : 0;
        int v = orig;
        #pragma unroll
        for (int off = 1; off <= 8; off <<= 1) {
            int n = __shfl_up(v, off, 64);
            if (t >= off) v += n;
        }
        if (t < 16) wScrI[t] = v - orig;
        if (t == 15) scal[0] = v;
    }
    __syncthreads();
    {
        bool need = (matchU[t] == (short)-2);
        u64 m = __ballot(need);
        if (need) {
            int rank = __popcll(m & ((1ull << lane) - 1ull));
            int idx = wScrI[wv] + rank;
            if (idx < BGCAP) bgListSh[idx] = (unsigned short)t;
        }
    }
    __syncthreads();

    // ---- staging: event slots -> contiguous pool right after bg0 ----
    const int bgCnt = min(scal[0], BGCAP);
    {
        const int nStage = min(totEv, EVcap);
        float2 sc[4]; unsigned short sp[4];
        #pragma unroll
        for (int k = 0; k < 4; k++) {
            int i = t + (k << 10);
            if (i < nStage) { int slot = evPool[i]; sp[k] = ldsEnt[slot]; sc[k] = bucketC[slot]; }
        }
        __syncthreads();
        #pragma unroll
        for (int k = 0; k < 4; k++) {
            int i = t + (k << 10);
            if (i < nStage) { ldsEnt[nBg0 + i] = sp[k]; bucketC[nBg0 + i] = sc[k]; }
        }
        if (t < bgCnt) vSteps[t] = ((const float2*)Vb)[bgListSh[t]];   // evPool dead
    }
    __syncthreads();

    // ---- beta: speculative argmins — 5 steps per wave share one stream ----
    for (int s0 = wv; s0 < bgCnt; s0 += 80) {
        u64 best[5]; float vxq[5], vyq[5]; int limq[5];
        int maxLim = 0;
        #pragma unroll
        for (int q = 0; q < 5; q++) {
            int s = s0 + 16 * q;
            best[q] = ~0ull; limq[q] = 0; vxq[q] = 0.0f; vyq[q] = 0.0f;
            if (s < bgCnt) {
                int js = bgListSh[s];
                float2 v = vSteps[s];
                vxq[q] = v.x; vyq[q] = v.y;
                limq[q] = nBg0 + min((int)evAx[js], EVcap);
                maxLim = max(maxLim, limq[q]);
            }
        }
        for (int i = lane; i < maxLim; i += 64) {
            float2 c = bucketC[i];
            unsigned p = ldsEnt[i];
            #pragma unroll
            for (int q = 0; q < 5; q++) {
                if (i < limq[q]) {
                    float d = pdist(vxq[q], vyq[q], c.x, c.y);
                    u64 pk = ((u64)__float_as_uint(d) << 32) | p;
                    if (pk < best[q]) best[q] = pk;
                }
            }
        }
        #pragma unroll
        for (int q = 0; q < 5; q++) {
            int s = s0 + 16 * q;
            if (s < bgCnt) {
                int js = bgListSh[s];
                int ne = evAx[js];
                u64 bq = best[q];
                for (int ei = EVcap + lane; ei < ne; ei += 64) {    // spill tail (rare)
                    if (ei - EVcap >= spillCap) break;
                    unsigned p = evSpillB[ei - EVcap];
                    float2 c = Ub2[p];
                    float d = pdist(vxq[q], vyq[q], c.x, c.y);
                    u64 pk = ((u64)__float_as_uint(d) << 32) | p;
                    if (pk < bq) bq = pk;
                }
                #pragma unroll
                for (int off = 32; off >= 1; off >>= 1) {
                    u64 o = __shfl_xor(bq, off, 64);
                    if (o < bq) bq = o;
                }
                if (lane == 0) specWin[s] = bq;       // bEnd/occA dead -> alias
            }
        }
    }
    __syncthreads();

    // ---- 2c: duplicate-winner check; parallel commit or sequential walk ----
    if (t < bgCnt) {
        u64 w0 = specWin[t];
        if (w0 != ~0ull) {
            unsigned myp = (unsigned)(w0 & 0xFFFFFFFFull);
            for (int s2 = 0; s2 < t; s2++) {
                u64 ws = specWin[s2];
                if (ws != ~0ull && (unsigned)(ws & 0xFFFFFFFFull) == myp) { scal[2] = 1; break; }
            }
        }
    }
    __syncthreads();
    float bgCost = 0.0f;
    if (scal[2] == 0) {
        // all winners distinct -> every speculative winner exact
        if (t < bgCnt) {
            int js = bgListSh[t];
            u64 w0 = specWin[t];
            if (w0 == ~0ull) matchU[js] = -1;
            else {
                matchU[js] = (short)(w0 & 0xFFFFFFFFull);
                costPartial = __fadd_rn(costPartial, __uint_as_float((unsigned)(w0 >> 32)));
            }
        }
    } else if (t < 64) {
        // sequential walk: apply events, O(1) validity check, rare recompute
        int applied = 0;
        for (int s = 0; s < bgCnt; s++) {
            int js = bgListSh[s];
            int target = evAx[js];
            for (int base = applied; base < target; base += 64) {
                int idx = base + t;
                if (idx < target) {
                    int p = (idx < EVcap) ? (int)ldsEnt[nBg0 + idx]
                                          : (int)evSpillB[idx - EVcap];
                    atomicOr(&bgbits[p >> 5], 1u << (p & 31));
                }
            }
            applied = target;
            __threadfence_block();
            u64 w0 = specWin[s];
            if (w0 == ~0ull) {
                if (t == 0) matchU[js] = -1;
            } else {
                int u = (int)(w0 & 0xFFFFFFFFull);
                bool setb = (bgbits[u >> 5] >> (u & 31)) & 1u;
                if (setb) {
                    if (t == 0) {
                        matchU[js] = (short)u;
                        atomicAnd(&bgbits[u >> 5], ~(1u << (u & 31)));
                        bgCost = __fadd_rn(bgCost, __uint_as_float((unsigned)(w0 >> 32)));
                    }
                } else {
                    float2 v = vSteps[s];
                    u64 best = ~0ull;
                    #pragma unroll
                    for (int i = 0; i < 2; i++) {
                        int wi = t * 2 + i;
                        unsigned bits = bgbits[wi];
                        int pb = wi << 5;
                        while (bits) {
                            int bpos = __builtin_ctz(bits);
                            bits &= bits - 1;
                            int p = pb + bpos;
                            float2 uu = Ub2[p];
                            float d = pdist(v.x, v.y, uu.x, uu.y);
                            u64 pk = ((u64)__float_as_uint(d) << 32) | (unsigned)p;
                            if (pk < best) best = pk;
                        }
                    }
                    #pragma unroll
                    for (int off = 32; off >= 1; off >>= 1) {
                        u64 o = __shfl_xor(best, off, 64);
                        if (o < best) best = o;
                    }
                    if (t == 0) {
                        if (best != ~0ull) {
                            int u2 = (int)(best & 0xFFFFFFFFull);
                            matchU[js] = (short)u2;
                            atomicAnd(&bgbits[u2 >> 5], ~(1u << (u2 & 31)));
                            bgCost = __fadd_rn(bgCost, __uint_as_float((unsigned)(best >> 32)));
                        } else matchU[js] = -1;
                    }
                }
                __threadfence_block();
            }
        }
    }
    __syncthreads();

    // ---- epilogue: cost reduction + outputs ----
    {
        float cp = costPartial;
        #pragma unroll
        for (int off = 32; off >= 1; off >>= 1) cp += __shfl_xor(cp, off, 64);
        if (lane == 0) wScrF[wv] = cp;
    }
    __syncthreads();
    if (t == 0) {
        float tot = bgCost;
        for (int i = 0; i < 16; ++i) tot = __fadd_rn(tot, wScrF[i]);
        out[(size_t)2 * B * NGT + b] = tot;
    }
    {
        int u = matchU[t];
        out[(size_t)b * NGT + t] = (float)u;
        out[(size_t)B * NGT + (size_t)b * NGT + t] = (u >= 0) ? (float)t : -1.0f;
    }
}

extern "C" void kernel_launch(void* const* d_in, const int* in_sizes, int n_in,
                              void* d_out, int out_size, void* d_ws, size_t ws_size,
                              hipStream_t stream) {
    const float* pred   = (const float*)d_in[0];
    const float* coords = (const float*)d_in[1];
    const int*   keys   = (const int*)d_in[2];
    const int*   masks  = (const int*)d_in[3];
    float* out = (float*)d_out;
    int B = in_sizes[2] / NGT;   // 8
    int useWs = (B == 8 && ws_size >= (size_t)WS_NEED) ? 1 : 0;
    int* hist = (int*)d_ws;
    unsigned short* labsP  = (unsigned short*)((char*)d_ws + LAB_OFF);
    unsigned short* spillP = (unsigned short*)((char*)d_ws + SPILL_OFF);
    if (useWs) {
        hipMemsetAsync(d_ws, 0, HIST_BYTES, stream);
        label_kernel<<<B * 4, 1024, 0, stream>>>(pred, keys, masks, hist, labsP);
    }
    matcher_kernel<<<B, 1024, 0, stream>>>(pred, coords, keys, masks, out,
                                           hist, labsP, spillP, useWs, B);
}